// Round 1
// baseline (439.951 us; speedup 1.0000x reference)
//
#include <hip/hip_runtime.h>

// Problem constants
#define BB 4
#define CC 256
#define TT 8
#define HH 16
#define WW 16
#define LL 8
#define NO 8
#define DD 32
#define BT 32          // B*T
#define VV 2048        // H*W*L
#define KIN 512        // feat+pos channels for GEMM
#define EPS_ 1e-5f

typedef short bf16x8 __attribute__((ext_vector_type(8)));
typedef float f32x4 __attribute__((ext_vector_type(4)));

static __device__ __forceinline__ float b2f(unsigned short u) {
    return __uint_as_float(((unsigned int)u) << 16);
}
static __device__ __forceinline__ float b2f_lo(unsigned int x) {
    return __uint_as_float(x << 16);
}
static __device__ __forceinline__ float b2f_hi(unsigned int x) {
    return __uint_as_float(x & 0xffff0000u);
}
static __device__ __forceinline__ unsigned short f2b(float f) {
    unsigned int x = __float_as_uint(f);
    unsigned int r = x + 0x7fffu + ((x >> 16) & 1u);   // RNE (finite values)
    return (unsigned short)(r >> 16);
}
static __device__ __forceinline__ float sigm(float x) {
    return 1.0f / (1.0f + __expf(-x));
}

// ---------------------------------------------------------------------------
// K0: convert Wp[:, 0:512] -> bf16 A-matrix; zero glob accumulator
// ---------------------------------------------------------------------------
__global__ __launch_bounds__(256) void k0_prep(const float* __restrict__ Wp,
                                               unsigned short* __restrict__ Wa,
                                               float* __restrict__ glob) {
    int i = blockIdx.x * 256 + threadIdx.x;
    if (i < CC * KIN) {
        int o = i >> 9, k = i & 511;
        Wa[i] = f2b(Wp[o * 768 + k]);
    } else if (i < CC * KIN + BT * CC) {
        glob[i - CC * KIN] = 0.0f;
    }
}

// ---------------------------------------------------------------------------
// K1: transpose feat/pos (B,C,T,v) -> srcT bf16 [n][v][512] (k<256 feat, else pos)
//     + accumulate glob sums via atomics
// ---------------------------------------------------------------------------
__global__ __launch_bounds__(256) void k1_transpose(const float* __restrict__ features,
                                                    const float* __restrict__ pos,
                                                    unsigned short* __restrict__ srcT,
                                                    float* __restrict__ glob) {
    const int n = blockIdx.x;          // 0..31
    const int v0 = blockIdx.y * 16;    // v tile of 16
    const int b = n >> 3, t = n & 7;
    const int tid = threadIdx.x;
    const int ty = tid >> 4;           // c offset within 16-chunk
    const int tx = tid & 15;           // v offset

    __shared__ unsigned short s1[16 * 520];   // [v][k] row stride 520 (16B-aligned rows)

    for (int cb = 0; cb < CC; cb += 16) {
        int c = cb + ty;
        size_t fidx = (((size_t)b * CC + c) * TT + t) * VV + v0 + tx;
        float f = features[fidx];
        float p = pos[fidx];
        s1[tx * 520 + c] = f2b(f);
        s1[tx * 520 + 256 + c] = f2b(p);
        // reduce f over the 16 v-lanes (lanes tx within group of 16)
        for (int d = 8; d > 0; d >>= 1) f += __shfl_down(f, d, 16);
        if (tx == 0) atomicAdd(&glob[n * CC + c], f);
    }
    __syncthreads();
    // write 16 rows x 512 shorts = 1024 uint4
    const size_t base = ((size_t)n * VV + v0) * KIN;
    for (int q = tid; q < 1024; q += 256) {
        int row = q >> 6;
        int koff = (q & 63) * 8;
        *(uint4*)&srcT[base + (size_t)row * KIN + koff] = *(const uint4*)&s1[row * 520 + koff];
    }
}

// ---------------------------------------------------------------------------
// K2: gterm[n][o] = bp[o] + sum_c Wp[o][512+c] * glob_mean[n][c]
// ---------------------------------------------------------------------------
__global__ __launch_bounds__(256) void k2_gterm(const float* __restrict__ glob,
                                                const float* __restrict__ Wp,
                                                const float* __restrict__ bp,
                                                float* __restrict__ gterm) {
    const int n = blockIdx.x;
    const int o = threadIdx.x;
    __shared__ float gl[CC];
    gl[o] = glob[n * CC + o] * (1.0f / (float)VV);
    __syncthreads();
    const float4* wrow = (const float4*)(Wp + (size_t)o * 768 + 512);
    const float4* g4 = (const float4*)gl;
    float s = bp[o];
    #pragma unroll 8
    for (int c = 0; c < 64; ++c) {
        float4 w = wrow[c], g = g4[c];
        s += w.x * g.x + w.y * g.y + w.z * g.z + w.w * g.w;
    }
    gterm[n * CC + o] = s;
}

// ---------------------------------------------------------------------------
// K3: GEMM  projT[n][v][o] = relu( sum_k Wa[o][k]*srcT[n][v][k] + gterm[n][o] )
//     128x128 tile, 4 waves (2x2 of 64x64), 16x16x32 bf16 MFMA, BK=32
// ---------------------------------------------------------------------------
__global__ __launch_bounds__(256) void k3_gemm(const unsigned short* __restrict__ Wa,
                                               const unsigned short* __restrict__ srcT,
                                               const float* __restrict__ gterm,
                                               unsigned short* __restrict__ projT) {
    const int n  = blockIdx.x;   // batch 0..31
    const int mb = blockIdx.y;   // 0..1   (o block)
    const int nb = blockIdx.z;   // 0..15  (v block)
    const int tid = threadIdx.x;
    const int m0 = mb * 128, v0 = nb * 128;

    __shared__ short As[128 * 40];   // [row][k] stride 40 shorts (80B, 16B-aligned)
    __shared__ short Bs[128 * 40];

    const int wv = tid >> 6;
    const int lane = tid & 63;
    const int wm = wv >> 1, wn = wv & 1;
    const int lr = lane & 15, lq = lane >> 4;

    f32x4 acc[4][4];
    #pragma unroll
    for (int i = 0; i < 4; ++i)
        #pragma unroll
        for (int j = 0; j < 4; ++j)
            acc[i][j] = (f32x4){0.f, 0.f, 0.f, 0.f};

    const int row = tid >> 1, half = tid & 1;
    const unsigned short* agp = Wa + (size_t)(m0 + row) * KIN + half * 16;
    const unsigned short* bgp = srcT + ((size_t)n * VV + v0 + row) * KIN + half * 16;
    short* asp = &As[row * 40 + half * 16];
    short* bsp = &Bs[row * 40 + half * 16];

    for (int k0 = 0; k0 < KIN; k0 += 32) {
        uint4 a0 = *(const uint4*)(agp + k0);
        uint4 a1 = *(const uint4*)(agp + k0 + 8);
        uint4 b0 = *(const uint4*)(bgp + k0);
        uint4 b1 = *(const uint4*)(bgp + k0 + 8);
        __syncthreads();
        *(uint4*)asp = a0; *(uint4*)(asp + 8) = a1;
        *(uint4*)bsp = b0; *(uint4*)(bsp + 8) = b1;
        __syncthreads();

        bf16x8 af[4], bf[4];
        #pragma unroll
        for (int i = 0; i < 4; ++i)
            af[i] = *(const bf16x8*)&As[(wm * 64 + i * 16 + lr) * 40 + lq * 8];
        #pragma unroll
        for (int j = 0; j < 4; ++j)
            bf[j] = *(const bf16x8*)&Bs[(wn * 64 + j * 16 + lr) * 40 + lq * 8];
        #pragma unroll
        for (int i = 0; i < 4; ++i)
            #pragma unroll
            for (int j = 0; j < 4; ++j)
                acc[i][j] = __builtin_amdgcn_mfma_f32_16x16x32_bf16(af[i], bf[j], acc[i][j], 0, 0, 0);
    }

    // epilogue: C/D layout col=lane&15 (v), row=(lane>>4)*4+r (o)
    #pragma unroll
    for (int i = 0; i < 4; ++i) {
        const int og = m0 + wm * 64 + i * 16 + lq * 4;
        float4 g = *(const float4*)(gterm + n * CC + og);
        #pragma unroll
        for (int j = 0; j < 4; ++j) {
            const int vg = v0 + wn * 64 + j * 16 + lr;
            float x0 = fmaxf(acc[i][j][0] + g.x, 0.0f);
            float x1 = fmaxf(acc[i][j][1] + g.y, 0.0f);
            float x2 = fmaxf(acc[i][j][2] + g.z, 0.0f);
            float x3 = fmaxf(acc[i][j][3] + g.w, 0.0f);
            ushort4 st;
            st.x = f2b(x0); st.y = f2b(x1); st.z = f2b(x2); st.w = f2b(x3);
            *(ushort4*)&projT[((size_t)n * VV + vg) * CC + og] = st;
        }
    }
}

// ---------------------------------------------------------------------------
// K4: per (n,v,head): offset/weight MLPs -> 8 corner {index, weight} pairs
// ---------------------------------------------------------------------------
__global__ __launch_bounds__(256) void k4_coef(const unsigned short* __restrict__ projT,
                                               const float* __restrict__ Wo,
                                               const float* __restrict__ bo,
                                               const float* __restrict__ Ww,
                                               const float* __restrict__ bw,
                                               int2* __restrict__ pairs) {
    __shared__ float sWo[96], sWw[64], sb[5];
    const int tid = threadIdx.x;
    if (tid < 96) sWo[tid] = Wo[tid];
    if (tid < 64) sWw[tid] = Ww[tid];
    if (tid < 3)  sb[tid] = bo[tid];
    if (tid < 2)  sb[3 + tid] = bw[tid];
    __syncthreads();

    const int g = blockIdx.x * 256 + tid;       // 0..524287
    const int n = g >> 14;
    const int rem = g & 16383;
    const int v = rem >> 3;
    const int hd = rem & 7;

    // load 32 bf16 osrc values (64B contiguous)
    const uint4* up = (const uint4*)(projT + ((size_t)n * VV + v) * CC + hd * DD);
    float osrc[32];
    #pragma unroll
    for (int q = 0; q < 4; ++q) {
        uint4 u = up[q];
        unsigned int ws4[4] = {u.x, u.y, u.z, u.w};
        #pragma unroll
        for (int e = 0; e < 4; ++e) {
            osrc[q * 8 + e * 2]     = b2f_lo(ws4[e]);
            osrc[q * 8 + e * 2 + 1] = b2f_hi(ws4[e]);
        }
    }

    float o0 = sb[0], o1 = sb[1], o2 = sb[2];
    float zw = sb[4] - sb[3];
    #pragma unroll
    for (int d = 0; d < DD; ++d) {
        float t = osrc[d];
        o0 += t * sWo[3 * d + 0];
        o1 += t * sWo[3 * d + 1];
        o2 += t * sWo[3 * d + 2];
        zw += t * (sWw[2 * d + 1] - sWw[2 * d]);
    }
    const float wgt = sigm(zw);                 // softmax(...)[...,1]

    const int h = v >> 7, w = (v >> 3) & 15, l = v & 7;
    float ph = fminf(fmaxf(h * (1.0f / 15.0f), EPS_), 1.0f - EPS_);
    float pw = fminf(fmaxf(w * (1.0f / 15.0f), EPS_), 1.0f - EPS_);
    float pl = fminf(fmaxf(l * (1.0f / 7.0f),  EPS_), 1.0f - EPS_);
    float lh = __logf(ph / (1.0f - ph));
    float lw = __logf(pw / (1.0f - pw));
    float ll = __logf(pl / (1.0f - pl));

    float sph = sigm(lh + sigm(o0));
    float spw = sigm(lw + sigm(o1));
    float spl = sigm(ll + sigm(o2));
    // pix = ((2*sp-1 + 1)*S - 1)/2 = sp*S - 0.5
    float pixh = sph * 16.0f - 0.5f;
    float pixw = spw * 16.0f - 0.5f;
    float pixl = spl * 8.0f  - 0.5f;

    float flh = floorf(pixh), flw = floorf(pixw), fll = floorf(pixl);
    float fh = pixh - flh, fw = pixw - flw, fl = pixl - fll;
    int ih = (int)flh, iw = (int)flw, il = (int)fll;

    int2* pp = pairs + (size_t)g * 8;
    #pragma unroll
    for (int dz = 0; dz < 2; ++dz)
        #pragma unroll
        for (int dy = 0; dy < 2; ++dy)
            #pragma unroll
            for (int dx = 0; dx < 2; ++dx) {
                int iz = ih + dz, iy = iw + dy, ix = il + dx;
                float wt = (dz ? fh : 1.0f - fh) * (dy ? fw : 1.0f - fw) * (dx ? fl : 1.0f - fl) * wgt;
                bool valid = ((unsigned)iz < 16u) && ((unsigned)iy < 16u) && ((unsigned)ix < 8u);
                int lin = valid ? ((iz * 16 + iy) * 8 + ix) : 0;
                float wv2 = valid ? wt : 0.0f;
                pp[dz * 4 + dy * 2 + dx] = make_int2(lin, __float_as_int(wv2));
            }
}

// ---------------------------------------------------------------------------
// K5: gather-accumulate: res[n][v][c] = sum over 64 (head,corner) of w * feat[n][vox][c]
//     block = 4 voxels x 64 lanes (4 channels each)
// ---------------------------------------------------------------------------
__global__ __launch_bounds__(256) void k5_gather(const unsigned short* __restrict__ srcT,
                                                 const int2* __restrict__ pairs,
                                                 unsigned short* __restrict__ res) {
    __shared__ int2 pr[256];
    const int n = blockIdx.x >> 9;       // 512 blocks per n
    const int vb = (blockIdx.x & 511) * 4;
    const int tid = threadIdx.x;
    pr[tid] = pairs[((size_t)n * VV + vb) * 64 + tid];
    __syncthreads();

    const int s = tid >> 6;              // local voxel 0..3
    const int lane = tid & 63;
    const int c4 = lane * 4;
    const unsigned short* slab = srcT + (size_t)n * VV * KIN;   // feat at k<256
    const int2* pe = &pr[s * 64];

    float a0 = 0.f, a1 = 0.f, a2 = 0.f, a3 = 0.f;
    for (int e = 0; e < 64; ++e) {
        int2 q = pe[e];
        float wq = __int_as_float(q.y);
        if (wq == 0.0f) continue;        // wave-uniform skip (border corners)
        ushort4 fv = *(const ushort4*)(slab + (size_t)q.x * KIN + c4);
        a0 = fmaf(wq, b2f(fv.x), a0);
        a1 = fmaf(wq, b2f(fv.y), a1);
        a2 = fmaf(wq, b2f(fv.z), a2);
        a3 = fmaf(wq, b2f(fv.w), a3);
    }
    const int v = vb + s;
    ushort4 st;
    st.x = f2b(a0); st.y = f2b(a1); st.z = f2b(a2); st.w = f2b(a3);
    *(ushort4*)&res[((size_t)n * VV + v) * CC + c4] = st;
}

// ---------------------------------------------------------------------------
// K6: out[b][c][t][v] = features[b][c][t][v] + res[n][v][c]   (LDS transpose)
// ---------------------------------------------------------------------------
__global__ __launch_bounds__(256) void k6_final(const float* __restrict__ features,
                                                const unsigned short* __restrict__ res,
                                                float* __restrict__ out) {
    const int n = blockIdx.x;            // 0..31
    const int c0 = blockIdx.y * 64;      // 0..3 -> c tile
    const int v0 = blockIdx.z * 64;      // 0..31 -> v tile
    const int b = n >> 3, t = n & 7;
    const int tid = threadIdx.x;
    const int ty = tid >> 6, tx = tid & 63;

    __shared__ unsigned short t6[64 * 66];

    for (int vv = ty; vv < 64; vv += 4)
        t6[vv * 66 + tx] = res[((size_t)n * VV + v0 + vv) * CC + c0 + tx];
    __syncthreads();
    for (int cc = ty; cc < 64; cc += 4) {
        int c = c0 + cc;
        size_t oidx = (((size_t)b * CC + c) * TT + t) * VV + v0 + tx;
        out[oidx] = features[oidx] + b2f(t6[tx * 66 + cc]);
    }
}

// ---------------------------------------------------------------------------
extern "C" void kernel_launch(void* const* d_in, const int* in_sizes, int n_in,
                              void* d_out, int out_size, void* d_ws, size_t ws_size,
                              hipStream_t stream) {
    (void)in_sizes; (void)n_in; (void)out_size; (void)ws_size;
    const float* features = (const float*)d_in[0];
    const float* pos      = (const float*)d_in[1];
    const float* Wp       = (const float*)d_in[2];
    const float* bp       = (const float*)d_in[3];
    const float* Wo       = (const float*)d_in[4];
    const float* bo       = (const float*)d_in[5];
    const float* Ww       = (const float*)d_in[6];
    const float* bw       = (const float*)d_in[7];
    float* out = (float*)d_out;

    char* ws = (char*)d_ws;
    unsigned short* srcT  = (unsigned short*)ws;                   // 64 MiB: [32][2048][512] bf16
    unsigned short* Wa    = (unsigned short*)(ws + 67108864);      // 256 KiB
    float*          glob  = (float*)(ws + 67371008);               // 32 KiB (zeroed by K0)
    float*          gterm = (float*)(ws + 67403776);               // 32 KiB
    unsigned short* projT = (unsigned short*)(ws + 67436544);      // 32 MiB: [32][2048][256] bf16
    int2*           pairs = (int2*)(ws + 100990976);               // 32 MiB: [32][2048][64] {idx,w}
    unsigned short* res   = projT;                                 // overlay (projT consumed by K4)

    k0_prep<<<544, 256, 0, stream>>>(Wp, Wa, glob);
    k1_transpose<<<dim3(32, 128), 256, 0, stream>>>(features, pos, srcT, glob);
    k2_gterm<<<32, 256, 0, stream>>>(glob, Wp, bp, gterm);
    k3_gemm<<<dim3(32, 2, 16), 256, 0, stream>>>(Wa, srcT, gterm, projT);
    k4_coef<<<2048, 256, 0, stream>>>(projT, Wo, bo, Ww, bw, pairs);
    k5_gather<<<16384, 256, 0, stream>>>(srcT, pairs, res);
    k6_final<<<dim3(32, 4, 32), 256, 0, stream>>>(features, res, out);
}

// Round 2
// 361.534 us; speedup vs baseline: 1.2169x; 1.2169x over previous
//
#include <hip/hip_runtime.h>

// Problem constants
#define BB 4
#define CC 256
#define TT 8
#define HH 16
#define WW 16
#define LL 8
#define NO 8
#define DD 32
#define BT 32          // B*T
#define VV 2048        // H*W*L
#define KIN 512        // feat+pos channels for GEMM
#define EPS_ 1e-5f

typedef short bf16x8 __attribute__((ext_vector_type(8)));
typedef float f32x4 __attribute__((ext_vector_type(4)));

static __device__ __forceinline__ float b2f(unsigned short u) {
    return __uint_as_float(((unsigned int)u) << 16);
}
static __device__ __forceinline__ float b2f_lo(unsigned int x) {
    return __uint_as_float(x << 16);
}
static __device__ __forceinline__ float b2f_hi(unsigned int x) {
    return __uint_as_float(x & 0xffff0000u);
}
static __device__ __forceinline__ unsigned short f2b(float f) {
    unsigned int x = __float_as_uint(f);
    unsigned int r = x + 0x7fffu + ((x >> 16) & 1u);   // RNE (finite values)
    return (unsigned short)(r >> 16);
}
static __device__ __forceinline__ unsigned int f2b_pk(float lo, float hi) {
    return (unsigned int)f2b(lo) | ((unsigned int)f2b(hi) << 16);
}
static __device__ __forceinline__ float sigm(float x) {
    return 1.0f / (1.0f + __expf(-x));
}

// ---------------------------------------------------------------------------
// K0: convert Wp[:, 0:512] -> bf16 A-matrix; zero glob accumulator
// ---------------------------------------------------------------------------
__global__ __launch_bounds__(256) void k0_prep(const float* __restrict__ Wp,
                                               unsigned short* __restrict__ Wa,
                                               float* __restrict__ glob) {
    int i = blockIdx.x * 256 + threadIdx.x;
    if (i < CC * KIN) {
        int o = i >> 9, k = i & 511;
        Wa[i] = f2b(Wp[o * 768 + k]);
    } else if (i < CC * KIN + BT * CC) {
        glob[i - CC * KIN] = 0.0f;
    }
}

// ---------------------------------------------------------------------------
// K1: transpose feat/pos (B,C,T,v) -> srcT bf16 [n][v][512] (k<256 feat, else pos)
//     + accumulate glob sums via atomics
// ---------------------------------------------------------------------------
__global__ __launch_bounds__(256) void k1_transpose(const float* __restrict__ features,
                                                    const float* __restrict__ pos,
                                                    unsigned short* __restrict__ srcT,
                                                    float* __restrict__ glob) {
    const int n = blockIdx.x;          // 0..31
    const int v0 = blockIdx.y * 16;    // v tile of 16
    const int b = n >> 3, t = n & 7;
    const int tid = threadIdx.x;
    const int ty = tid >> 4;           // c offset within 16-chunk
    const int tx = tid & 15;           // v offset

    __shared__ unsigned short s1[16 * 520];   // [v][k] row stride 520 (16B-aligned rows)

    for (int cb = 0; cb < CC; cb += 16) {
        int c = cb + ty;
        size_t fidx = (((size_t)b * CC + c) * TT + t) * VV + v0 + tx;
        float f = features[fidx];
        float p = pos[fidx];
        s1[tx * 520 + c] = f2b(f);
        s1[tx * 520 + 256 + c] = f2b(p);
        // reduce f over the 16 v-lanes (lanes tx within group of 16)
        for (int d = 8; d > 0; d >>= 1) f += __shfl_down(f, d, 16);
        if (tx == 0) atomicAdd(&glob[n * CC + c], f);
    }
    __syncthreads();
    // write 16 rows x 512 shorts = 1024 uint4
    const size_t base = ((size_t)n * VV + v0) * KIN;
    for (int q = tid; q < 1024; q += 256) {
        int row = q >> 6;
        int koff = (q & 63) * 8;
        *(uint4*)&srcT[base + (size_t)row * KIN + koff] = *(const uint4*)&s1[row * 520 + koff];
    }
}

// ---------------------------------------------------------------------------
// K2: gterm[n][o] = bp[o] + sum_c Wp[o][512+c] * glob_mean[n][c]
// ---------------------------------------------------------------------------
__global__ __launch_bounds__(256) void k2_gterm(const float* __restrict__ glob,
                                                const float* __restrict__ Wp,
                                                const float* __restrict__ bp,
                                                float* __restrict__ gterm) {
    const int n = blockIdx.x;
    const int o = threadIdx.x;
    __shared__ float gl[CC];
    gl[o] = glob[n * CC + o] * (1.0f / (float)VV);
    __syncthreads();
    const float4* wrow = (const float4*)(Wp + (size_t)o * 768 + 512);
    const float4* g4 = (const float4*)gl;
    float s = bp[o];
    #pragma unroll 8
    for (int c = 0; c < 64; ++c) {
        float4 w = wrow[c], g = g4[c];
        s += w.x * g.x + w.y * g.y + w.z * g.z + w.w * g.w;
    }
    gterm[n * CC + o] = s;
}

// ---------------------------------------------------------------------------
// K3: GEMM  projT[n][v][o] = relu( sum_k Wa[o][k]*srcT[n][v][k] + gterm[n][o] )
//     128x128 tile, 4 waves (2x2 of 64x64), 16x16x32 bf16 MFMA, BK=32
// ---------------------------------------------------------------------------
__global__ __launch_bounds__(256) void k3_gemm(const unsigned short* __restrict__ Wa,
                                               const unsigned short* __restrict__ srcT,
                                               const float* __restrict__ gterm,
                                               unsigned short* __restrict__ projT) {
    const int n  = blockIdx.x;   // batch 0..31
    const int mb = blockIdx.y;   // 0..1   (o block)
    const int nb = blockIdx.z;   // 0..15  (v block)
    const int tid = threadIdx.x;
    const int m0 = mb * 128, v0 = nb * 128;

    __shared__ short As[128 * 40];   // [row][k] stride 40 shorts (80B, 16B-aligned)
    __shared__ short Bs[128 * 40];

    const int wv = tid >> 6;
    const int lane = tid & 63;
    const int wm = wv >> 1, wn = wv & 1;
    const int lr = lane & 15, lq = lane >> 4;

    f32x4 acc[4][4];
    #pragma unroll
    for (int i = 0; i < 4; ++i)
        #pragma unroll
        for (int j = 0; j < 4; ++j)
            acc[i][j] = (f32x4){0.f, 0.f, 0.f, 0.f};

    const int row = tid >> 1, half = tid & 1;
    const unsigned short* agp = Wa + (size_t)(m0 + row) * KIN + half * 16;
    const unsigned short* bgp = srcT + ((size_t)n * VV + v0 + row) * KIN + half * 16;
    short* asp = &As[row * 40 + half * 16];
    short* bsp = &Bs[row * 40 + half * 16];

    for (int k0 = 0; k0 < KIN; k0 += 32) {
        uint4 a0 = *(const uint4*)(agp + k0);
        uint4 a1 = *(const uint4*)(agp + k0 + 8);
        uint4 b0 = *(const uint4*)(bgp + k0);
        uint4 b1 = *(const uint4*)(bgp + k0 + 8);
        __syncthreads();
        *(uint4*)asp = a0; *(uint4*)(asp + 8) = a1;
        *(uint4*)bsp = b0; *(uint4*)(bsp + 8) = b1;
        __syncthreads();

        bf16x8 af[4], bf[4];
        #pragma unroll
        for (int i = 0; i < 4; ++i)
            af[i] = *(const bf16x8*)&As[(wm * 64 + i * 16 + lr) * 40 + lq * 8];
        #pragma unroll
        for (int j = 0; j < 4; ++j)
            bf[j] = *(const bf16x8*)&Bs[(wn * 64 + j * 16 + lr) * 40 + lq * 8];
        #pragma unroll
        for (int i = 0; i < 4; ++i)
            #pragma unroll
            for (int j = 0; j < 4; ++j)
                acc[i][j] = __builtin_amdgcn_mfma_f32_16x16x32_bf16(af[i], bf[j], acc[i][j], 0, 0, 0);
    }

    // epilogue: C/D layout col=lane&15 (v), row=(lane>>4)*4+r (o)
    #pragma unroll
    for (int i = 0; i < 4; ++i) {
        const int og = m0 + wm * 64 + i * 16 + lq * 4;
        float4 g = *(const float4*)(gterm + n * CC + og);
        #pragma unroll
        for (int j = 0; j < 4; ++j) {
            const int vg = v0 + wn * 64 + j * 16 + lr;
            float x0 = fmaxf(acc[i][j][0] + g.x, 0.0f);
            float x1 = fmaxf(acc[i][j][1] + g.y, 0.0f);
            float x2 = fmaxf(acc[i][j][2] + g.z, 0.0f);
            float x3 = fmaxf(acc[i][j][3] + g.w, 0.0f);
            ushort4 st;
            st.x = f2b(x0); st.y = f2b(x1); st.z = f2b(x2); st.w = f2b(x3);
            *(ushort4*)&projT[((size_t)n * VV + vg) * CC + og] = st;
        }
    }
}

// ---------------------------------------------------------------------------
// K4: per (n,v,head): offset/weight MLPs -> 8 corner {index, weight} pairs
// ---------------------------------------------------------------------------
__global__ __launch_bounds__(256) void k4_coef(const unsigned short* __restrict__ projT,
                                               const float* __restrict__ Wo,
                                               const float* __restrict__ bo,
                                               const float* __restrict__ Ww,
                                               const float* __restrict__ bw,
                                               int2* __restrict__ pairs) {
    __shared__ float sWo[96], sWw[64], sb[5];
    const int tid = threadIdx.x;
    if (tid < 96) sWo[tid] = Wo[tid];
    if (tid < 64) sWw[tid] = Ww[tid];
    if (tid < 3)  sb[tid] = bo[tid];
    if (tid < 2)  sb[3 + tid] = bw[tid];
    __syncthreads();

    const int g = blockIdx.x * 256 + tid;       // 0..524287
    const int n = g >> 14;
    const int rem = g & 16383;
    const int v = rem >> 3;
    const int hd = rem & 7;

    // load 32 bf16 osrc values (64B contiguous)
    const uint4* up = (const uint4*)(projT + ((size_t)n * VV + v) * CC + hd * DD);
    float osrc[32];
    #pragma unroll
    for (int q = 0; q < 4; ++q) {
        uint4 u = up[q];
        unsigned int ws4[4] = {u.x, u.y, u.z, u.w};
        #pragma unroll
        for (int e = 0; e < 4; ++e) {
            osrc[q * 8 + e * 2]     = b2f_lo(ws4[e]);
            osrc[q * 8 + e * 2 + 1] = b2f_hi(ws4[e]);
        }
    }

    float o0 = sb[0], o1 = sb[1], o2 = sb[2];
    float zw = sb[4] - sb[3];
    #pragma unroll
    for (int d = 0; d < DD; ++d) {
        float t = osrc[d];
        o0 += t * sWo[3 * d + 0];
        o1 += t * sWo[3 * d + 1];
        o2 += t * sWo[3 * d + 2];
        zw += t * (sWw[2 * d + 1] - sWw[2 * d]);
    }
    const float wgt = sigm(zw);                 // softmax(...)[...,1]

    const int h = v >> 7, w = (v >> 3) & 15, l = v & 7;
    float ph = fminf(fmaxf(h * (1.0f / 15.0f), EPS_), 1.0f - EPS_);
    float pw = fminf(fmaxf(w * (1.0f / 15.0f), EPS_), 1.0f - EPS_);
    float pl = fminf(fmaxf(l * (1.0f / 7.0f),  EPS_), 1.0f - EPS_);
    float lh = __logf(ph / (1.0f - ph));
    float lw = __logf(pw / (1.0f - pw));
    float ll = __logf(pl / (1.0f - pl));

    float sph = sigm(lh + sigm(o0));
    float spw = sigm(lw + sigm(o1));
    float spl = sigm(ll + sigm(o2));
    // pix = ((2*sp-1 + 1)*S - 1)/2 = sp*S - 0.5
    float pixh = sph * 16.0f - 0.5f;
    float pixw = spw * 16.0f - 0.5f;
    float pixl = spl * 8.0f  - 0.5f;

    float flh = floorf(pixh), flw = floorf(pixw), fll = floorf(pixl);
    float fh = pixh - flh, fw = pixw - flw, fl = pixl - fll;
    int ih = (int)flh, iw = (int)flw, il = (int)fll;

    int2* pp = pairs + (size_t)g * 8;
    #pragma unroll
    for (int dz = 0; dz < 2; ++dz)
        #pragma unroll
        for (int dy = 0; dy < 2; ++dy)
            #pragma unroll
            for (int dx = 0; dx < 2; ++dx) {
                int iz = ih + dz, iy = iw + dy, ix = il + dx;
                float wt = (dz ? fh : 1.0f - fh) * (dy ? fw : 1.0f - fw) * (dx ? fl : 1.0f - fl) * wgt;
                bool valid = ((unsigned)iz < 16u) && ((unsigned)iy < 16u) && ((unsigned)ix < 8u);
                int lin = valid ? ((iz * 16 + iy) * 8 + ix) : 0;
                float wv2 = valid ? wt : 0.0f;
                pp[dz * 4 + dy * 2 + dx] = make_int2(lin, __float_as_int(wv2));
            }
}

// ---------------------------------------------------------------------------
// K5: gather-accumulate: res[n][v][c] = sum over 64 (head,corner) of w * feat[vox][c]
//     Block = 8 voxels. Wave = 2 voxels (32 lanes x 8 channels each).
//     Branch-free, 8-deep unroll -> 8 outstanding 16B loads per wave.
// ---------------------------------------------------------------------------
__global__ __launch_bounds__(256) void k5_gather(const unsigned short* __restrict__ srcT,
                                                 const int2* __restrict__ pairs,
                                                 unsigned short* __restrict__ res) {
    __shared__ int2 pr[8 * 64];
    const int n  = blockIdx.x >> 8;          // 256 blocks per n
    const int vb = (blockIdx.x & 255) * 8;   // 8 voxels per block
    const int tid = threadIdx.x;

    // stage 512 int2 (4 KB) of corner pairs: 256 threads x 16B
    {
        const int2* src = pairs + ((size_t)n * VV + vb) * 64;
        *(int4*)&pr[tid * 2] = *(const int4*)&src[tid * 2];
    }
    __syncthreads();

    const int s = tid >> 5;                  // local voxel 0..7 (half-wave each)
    const int lane = tid & 31;
    const int c8 = lane * 8;                 // 8 channels per lane
    const unsigned short* slab = srcT + (size_t)n * VV * KIN + c8;  // feat at k<256
    const int2* pe = &pr[s * 64];

    float a0 = 0.f, a1 = 0.f, a2 = 0.f, a3 = 0.f;
    float a4 = 0.f, a5 = 0.f, a6 = 0.f, a7 = 0.f;

    #pragma unroll 1
    for (int e = 0; e < 64; e += 8) {
        uint4 f[8];
        float w[8];
        #pragma unroll
        for (int u = 0; u < 8; ++u) {
            int2 q = pe[e + u];
            w[u] = __int_as_float(q.y);
            f[u] = *(const uint4*)(slab + (size_t)q.x * KIN);
        }
        #pragma unroll
        for (int u = 0; u < 8; ++u) {
            a0 = fmaf(w[u], b2f_lo(f[u].x), a0);
            a1 = fmaf(w[u], b2f_hi(f[u].x), a1);
            a2 = fmaf(w[u], b2f_lo(f[u].y), a2);
            a3 = fmaf(w[u], b2f_hi(f[u].y), a3);
            a4 = fmaf(w[u], b2f_lo(f[u].z), a4);
            a5 = fmaf(w[u], b2f_hi(f[u].z), a5);
            a6 = fmaf(w[u], b2f_lo(f[u].w), a6);
            a7 = fmaf(w[u], b2f_hi(f[u].w), a7);
        }
    }

    uint4 st;
    st.x = f2b_pk(a0, a1);
    st.y = f2b_pk(a2, a3);
    st.z = f2b_pk(a4, a5);
    st.w = f2b_pk(a6, a7);
    *(uint4*)&res[((size_t)n * VV + vb + s) * CC + c8] = st;
}

// ---------------------------------------------------------------------------
// K6: out[b][c][t][v] = features[b][c][t][v] + res[n][v][c]   (LDS transpose)
// ---------------------------------------------------------------------------
__global__ __launch_bounds__(256) void k6_final(const float* __restrict__ features,
                                                const unsigned short* __restrict__ res,
                                                float* __restrict__ out) {
    const int n = blockIdx.x;            // 0..31
    const int c0 = blockIdx.y * 64;      // 0..3 -> c tile
    const int v0 = blockIdx.z * 64;      // 0..31 -> v tile
    const int b = n >> 3, t = n & 7;
    const int tid = threadIdx.x;
    const int ty = tid >> 6, tx = tid & 63;

    __shared__ unsigned short t6[64 * 66];

    for (int vv = ty; vv < 64; vv += 4)
        t6[vv * 66 + tx] = res[((size_t)n * VV + v0 + vv) * CC + c0 + tx];
    __syncthreads();
    for (int cc = ty; cc < 64; cc += 4) {
        int c = c0 + cc;
        size_t oidx = (((size_t)b * CC + c) * TT + t) * VV + v0 + tx;
        out[oidx] = features[oidx] + b2f(t6[tx * 66 + cc]);
    }
}

// ---------------------------------------------------------------------------
extern "C" void kernel_launch(void* const* d_in, const int* in_sizes, int n_in,
                              void* d_out, int out_size, void* d_ws, size_t ws_size,
                              hipStream_t stream) {
    (void)in_sizes; (void)n_in; (void)out_size; (void)ws_size;
    const float* features = (const float*)d_in[0];
    const float* pos      = (const float*)d_in[1];
    const float* Wp       = (const float*)d_in[2];
    const float* bp       = (const float*)d_in[3];
    const float* Wo       = (const float*)d_in[4];
    const float* bo       = (const float*)d_in[5];
    const float* Ww       = (const float*)d_in[6];
    const float* bw       = (const float*)d_in[7];
    float* out = (float*)d_out;

    char* ws = (char*)d_ws;
    unsigned short* srcT  = (unsigned short*)ws;                   // 64 MiB: [32][2048][512] bf16
    unsigned short* Wa    = (unsigned short*)(ws + 67108864);      // 256 KiB
    float*          glob  = (float*)(ws + 67371008);               // 32 KiB (zeroed by K0)
    float*          gterm = (float*)(ws + 67403776);               // 32 KiB
    unsigned short* projT = (unsigned short*)(ws + 67436544);      // 32 MiB: [32][2048][256] bf16
    int2*           pairs = (int2*)(ws + 100990976);               // 32 MiB: [32][2048][64] {idx,w}
    unsigned short* res   = projT;                                 // overlay (projT consumed by K4)

    k0_prep<<<544, 256, 0, stream>>>(Wp, Wa, glob);
    k1_transpose<<<dim3(32, 128), 256, 0, stream>>>(features, pos, srcT, glob);
    k2_gterm<<<32, 256, 0, stream>>>(glob, Wp, bp, gterm);
    k3_gemm<<<dim3(32, 2, 16), 256, 0, stream>>>(Wa, srcT, gterm, projT);
    k4_coef<<<2048, 256, 0, stream>>>(projT, Wo, bo, Ww, bw, pairs);
    k5_gather<<<8192, 256, 0, stream>>>(srcT, pairs, res);
    k6_final<<<dim3(32, 4, 32), 256, 0, stream>>>(features, res, out);
}